// Round 6
// baseline (540.274 us; speedup 1.0000x reference)
//
#include <hip/hip_runtime.h>
#include <cmath>

// Problem constants
#define TT 8192
#define NE 256
#define ND 7168
#define NGRP 8
#define TOPKG 4
#define TOPK 8
#define ROUTE_SCALE 2.5f

#define NKT32 (ND / 32)    // 224 k-chunks of 32
#define NNT16 (NE / 16)    // 16 n-tiles of 16
#define TM 64              // tokens per block

typedef _Float16 half8_ __attribute__((ext_vector_type(8)));
typedef float float4_ __attribute__((ext_vector_type(4)));

// ---------------------------------------------------------------------------
// k-permutation (shared by A and B): physical MFMA k-slot (q, j) holds
// LOGICAL k = 4*q + (j&3) + 16*(j>>2) within the 32-k chunk. This makes the
// GEMM's direct-from-global A load 64B-contiguous per token row.
//
// conv_w: w (fp32 [E][D]) -> permuted fragment-ordered fp16 hi/lo for
// mfma_f32_16x16x32_f16. B-frag: lane holds B[k-slot (q=lane>>4, j)][n=lane&15].
__global__ __launch_bounds__(256) void conv_w_kernel(
    const float* __restrict__ w, _Float16* __restrict__ whF,
    _Float16* __restrict__ wlF)
{
    const int gid  = blockIdx.x * 256 + threadIdx.x;   // NNT16*NKT32*64 total
    const int lane = gid & 63;
    const int pair = gid >> 6;            // nt*NKT32 + kt
    const int kt   = pair % NKT32;
    const int nt   = pair / NKT32;
    const int n = nt * 16 + (lane & 15);
    const int q = lane >> 4;
    const float* src = w + (size_t)n * ND + kt * 32 + q * 4;
    const float4 v0 = *reinterpret_cast<const float4*>(src);       // k: 4q..4q+3
    const float4 v1 = *reinterpret_cast<const float4*>(src + 16);  // k: 16+4q..+3
    const float vs[8] = {v0.x, v0.y, v0.z, v0.w, v1.x, v1.y, v1.z, v1.w};
    half8_ h, l;
    #pragma unroll
    for (int j = 0; j < 8; ++j) {
        const _Float16 hi = (_Float16)vs[j];
        h[j] = hi;
        l[j] = (_Float16)(vs[j] - (float)hi);
    }
    const size_t off = ((size_t)pair * 64 + lane) * 8;
    *reinterpret_cast<half8_*>(whF + off) = h;
    *reinterpret_cast<half8_*>(wlF + off) = l;
}

// ---------------------------------------------------------------------------
// LDS-free, barrier-free split-fp16 MFMA GEMM.
// Block = 256 threads (4 waves) = 64 tokens x 256 experts; wave = 64 tok x 64
// exp = 4x4 tiles of 16x16x32. A comes straight from global x via the
// k-permuted layout: lane reads x[t0+mt*16+(lane&15)][k0+(lane>>4)*4 + c*16]
// -> per instruction 16 rows x 64B contiguous. The 4 waves share the same A
// addresses (L1 dedupe). fp32->hi/lo fp16 conversion in registers (VALU pipe,
// overlaps MFMA). No __syncthreads anywhere: A prefetched 2 chunks ahead,
// B (L2-resident fragment buffers) 1 chunk ahead, all loads stay in flight.
__global__ __launch_bounds__(256, 2) void gemm_kernel(
    const float* __restrict__ x, const _Float16* __restrict__ whF,
    const _Float16* __restrict__ wlF, float* __restrict__ partial,
    int K_slice)
{
    const int tid  = threadIdx.x;
    const int lane = tid & 63;
    const int wv   = tid >> 6;            // wave -> 64-expert quarter
    const int t0   = blockIdx.x * TM;
    const int ks   = blockIdx.y;
    const int kbeg = ks * K_slice;
    const int nchunks = K_slice >> 5;     // 28/56/112 — always even

    const int rm = lane & 15;             // token row within 16-tile
    const int q  = lane >> 4;             // lane quad -> k-offset q*4 (logical)

    float4_ acc[4][4];
    #pragma unroll
    for (int i = 0; i < 4; ++i)
        #pragma unroll
        for (int j = 0; j < 4; ++j) acc[i][j] = (float4_)0.0f;

    // A base: row (t0+rm), k = kbeg + q*4; per (mt,c,chunk): +mt*16*ND + c*16 + chunk*32
    const float* xb = x + (size_t)(t0 + rm) * ND + kbeg + q * 4;
    // B base: wave's experts wv*64 -> global n-tiles wv*4+nt
    const size_t bb = (((size_t)(wv * 4) * NKT32 + (kbeg >> 5)) * 64 + lane) * 8;
    const _Float16* bhp = whF + bb;       // +nt*NKT32*512 per n-tile, +c*512 per chunk
    const _Float16* blp = wlF + bb;

    float4 xv[2][4][2];    // [slot][mt][c] raw fp32 A fragments
    half8_ Bf[2][8];       // [slot][nt*2 + (0=hi,1=lo)]

    // Prologue: A(0)->slot0, A(1)->slot1, B(0)->slot0.
    #pragma unroll
    for (int mt = 0; mt < 4; ++mt) {
        const float* p = xb + (size_t)(mt * 16) * ND;
        xv[0][mt][0] = *reinterpret_cast<const float4*>(p);
        xv[0][mt][1] = *reinterpret_cast<const float4*>(p + 16);
        xv[1][mt][0] = *reinterpret_cast<const float4*>(p + 32);
        xv[1][mt][1] = *reinterpret_cast<const float4*>(p + 48);
    }
    #pragma unroll
    for (int nt = 0; nt < 4; ++nt) {
        Bf[0][nt * 2 + 0] = *reinterpret_cast<const half8_*>(bhp + (size_t)nt * NKT32 * 512);
        Bf[0][nt * 2 + 1] = *reinterpret_cast<const half8_*>(blp + (size_t)nt * NKT32 * 512);
    }

#define STEP(P, C)                                                             \
    {                                                                          \
        /* 1. convert raw A(C) -> hi/lo fp16 frags (VALU; slot P freed) */     \
        half8_ ah[4], al[4];                                                   \
        _Pragma("unroll")                                                      \
        for (int mt = 0; mt < 4; ++mt) {                                       \
            const float4 v0 = xv[P][mt][0];                                    \
            const float4 v1 = xv[P][mt][1];                                    \
            const float vs[8] = {v0.x, v0.y, v0.z, v0.w,                       \
                                 v1.x, v1.y, v1.z, v1.w};                      \
            _Pragma("unroll")                                                  \
            for (int j = 0; j < 8; ++j) {                                      \
                const _Float16 hi = (_Float16)vs[j];                           \
                ah[mt][j] = hi;                                                \
                al[mt][j] = (_Float16)(vs[j] - (float)hi);                     \
            }                                                                  \
        }                                                                      \
        /* 2. issue A(C+2) -> slot P */                                        \
        if ((C) + 2 < nchunks) {                                               \
            _Pragma("unroll")                                                  \
            for (int mt = 0; mt < 4; ++mt) {                                   \
                const float* p = xb + (size_t)(mt * 16) * ND + ((C) + 2) * 32; \
                xv[P][mt][0] = *reinterpret_cast<const float4*>(p);            \
                xv[P][mt][1] = *reinterpret_cast<const float4*>(p + 16);       \
            }                                                                  \
        }                                                                      \
        /* 3. issue B(C+1) -> slot P^1 */                                      \
        if ((C) + 1 < nchunks) {                                               \
            _Pragma("unroll")                                                  \
            for (int nt = 0; nt < 4; ++nt) {                                   \
                const size_t o = (size_t)nt * NKT32 * 512 + ((C) + 1) * 512;   \
                Bf[(P) ^ 1][nt * 2 + 0] =                                      \
                    *reinterpret_cast<const half8_*>(bhp + o);                 \
                Bf[(P) ^ 1][nt * 2 + 1] =                                      \
                    *reinterpret_cast<const half8_*>(blp + o);                 \
            }                                                                  \
        }                                                                      \
        /* 4. 48 MFMAs, product-major: 16 independent per phase */             \
        _Pragma("unroll")                                                      \
        for (int mt = 0; mt < 4; ++mt)                                         \
            _Pragma("unroll")                                                  \
            for (int nt = 0; nt < 4; ++nt)                                     \
                acc[mt][nt] = __builtin_amdgcn_mfma_f32_16x16x32_f16(          \
                    ah[mt], Bf[P][nt * 2 + 0], acc[mt][nt], 0, 0, 0);          \
        _Pragma("unroll")                                                      \
        for (int mt = 0; mt < 4; ++mt)                                         \
            _Pragma("unroll")                                                  \
            for (int nt = 0; nt < 4; ++nt)                                     \
                acc[mt][nt] = __builtin_amdgcn_mfma_f32_16x16x32_f16(          \
                    al[mt], Bf[P][nt * 2 + 0], acc[mt][nt], 0, 0, 0);          \
        _Pragma("unroll")                                                      \
        for (int mt = 0; mt < 4; ++mt)                                         \
            _Pragma("unroll")                                                  \
            for (int nt = 0; nt < 4; ++nt)                                     \
                acc[mt][nt] = __builtin_amdgcn_mfma_f32_16x16x32_f16(          \
                    ah[mt], Bf[P][nt * 2 + 1], acc[mt][nt], 0, 0, 0);          \
    }

    for (int c = 0; c < nchunks; c += 2) {
        STEP(0, c)
        STEP(1, c + 1)
    }
#undef STEP

    // Epilogue: C/D layout col=lane&15, row=quad*4+reg (r2/r3-verified)
    #pragma unroll
    for (int mt = 0; mt < 4; ++mt)
        #pragma unroll
        for (int r = 0; r < 4; ++r) {
            const int t = t0 + mt * 16 + q * 4 + r;
            float* rowp = partial + ((size_t)ks * TT + t) * NE;
            #pragma unroll
            for (int nt = 0; nt < 4; ++nt)
                rowp[wv * 64 + nt * 16 + rm] = acc[mt][nt][r];
        }
}

// ---------------------------------------------------------------------------
// Routing: one 64-lane wave per token; lane handles 4 experts.
__global__ __launch_bounds__(256) void routing_kernel(
    const float* __restrict__ partial, const float* __restrict__ bias,
    float* __restrict__ out_w, float* __restrict__ out_i, int kslices)
{
    const int lane = threadIdx.x & 63;
    const int t = blockIdx.x * 4 + (threadIdx.x >> 6);

    float4 a = make_float4(0.f, 0.f, 0.f, 0.f);
    for (int s = 0; s < kslices; ++s) {
        const float4 p = *reinterpret_cast<const float4*>(
            partial + ((size_t)s * TT + t) * NE + lane * 4);
        a.x += p.x; a.y += p.y; a.z += p.z; a.w += p.w;
    }
    const float4 b4 = *reinterpret_cast<const float4*>(bias + lane * 4);
    const float lg[4] = {a.x, a.y, a.z, a.w};
    const float bs[4] = {b4.x, b4.y, b4.z, b4.w};
    float sg[4], sv[4];
    #pragma unroll
    for (int j = 0; j < 4; ++j) {
        sg[j] = 1.0f / (1.0f + expf(-lg[j]));   // original sigmoid score
        sv[j] = sg[j] + bs[j];                  // biased score
    }

    // Per-group (8 lanes = 32 experts) top-2 sum
    float m1 = -1e30f, m2 = -1e30f;
    #pragma unroll
    for (int j = 0; j < 4; ++j) {
        if (sv[j] > m1)      { m2 = m1; m1 = sv[j]; }
        else if (sv[j] > m2) { m2 = sv[j]; }
    }
    #pragma unroll
    for (int off = 1; off <= 4; off <<= 1) {
        const float o1 = __shfl_xor(m1, off, 64);
        const float o2 = __shfl_xor(m2, off, 64);
        if (o1 > m1) { m2 = fmaxf(m1, o2); m1 = o1; }
        else         { m2 = fmaxf(m2, o1); }
    }
    const float gs = m1 + m2;

    // All 8 group scores on every lane; serial top-4 (lowest index on ties)
    float gv[NGRP];
    #pragma unroll
    for (int g = 0; g < NGRP; ++g) gv[g] = __shfl(gs, g * 8, 64);
    unsigned keep = 0;
    #pragma unroll
    for (int r = 0; r < TOPKG; ++r) {
        int best = 0; float bvv = -1e30f;
        #pragma unroll
        for (int g = 0; g < NGRP; ++g) {
            const bool taken = (keep >> g) & 1u;
            if (!taken && gv[g] > bvv) { bvv = gv[g]; best = g; }
        }
        keep |= 1u << best;
    }

    // Masked scores (exact 0.0f for dropped groups, matching sg*mask)
    const bool kept = (keep >> (lane >> 3)) & 1u;
    float rv[4];
    #pragma unroll
    for (int j = 0; j < 4; ++j) rv[j] = kept ? sv[j] : 0.0f;

    // 8x wave argmax extraction carrying (biased val, idx, orig sigmoid)
    float wsum = 0.f, myw = 0.f;
    int myi = 0;
    #pragma unroll
    for (int r = 0; r < TOPK; ++r) {
        float bv = -1e30f, bo = 0.f; int bi = 0x7fffffff;
        #pragma unroll
        for (int j = 0; j < 4; ++j)
            if (rv[j] > bv) { bv = rv[j]; bi = lane * 4 + j; bo = sg[j]; }
        #pragma unroll
        for (int off = 1; off < 64; off <<= 1) {
            const float ov = __shfl_xor(bv, off, 64);
            const int   oi = __shfl_xor(bi, off, 64);
            const float oo = __shfl_xor(bo, off, 64);
            if (ov > bv || (ov == bv && oi < bi)) { bv = ov; bi = oi; bo = oo; }
        }
        if ((bi >> 2) == lane) rv[bi & 3] = -1e30f;   // remove winner
        wsum += bo;
        if (lane == r) { myw = bo; myi = bi; }
    }
    const float scale = ROUTE_SCALE / wsum;
    if (lane < TOPK) {
        out_w[(size_t)t * TOPK + lane] = myw * scale;
        out_i[(size_t)t * TOPK + lane] = (float)myi;  // fp32-encoded indices
    }
}

// ---------------------------------------------------------------------------
extern "C" void kernel_launch(void* const* d_in, const int* in_sizes, int n_in,
                              void* d_out, int out_size, void* d_ws, size_t ws_size,
                              hipStream_t stream) {
    const float* x    = (const float*)d_in[0];
    const float* w    = (const float*)d_in[1];
    const float* bias = (const float*)d_in[2];

    float* out_w = (float*)d_out;
    float* out_i = (float*)d_out + (size_t)TT * TOPK;

    // ws layout: whF | wlF | partial[kslices][TT][NE]
    const size_t wfrag_bytes = (size_t)NE * ND * sizeof(_Float16);  // 3.67 MB
    _Float16* whF = (_Float16*)d_ws;
    _Float16* wlF = (_Float16*)((char*)d_ws + wfrag_bytes);
    float* partial = (float*)((char*)d_ws + 2 * wfrag_bytes);

    const size_t part1 = (size_t)TT * NE * sizeof(float);           // 8 MB
    int kslices = 1;
    if      (ws_size >= 2 * wfrag_bytes + 8 * part1) kslices = 8;
    else if (ws_size >= 2 * wfrag_bytes + 4 * part1) kslices = 4;
    else if (ws_size >= 2 * wfrag_bytes + 2 * part1) kslices = 2;
    const int K_slice = ND / kslices;

    conv_w_kernel<<<(NNT16 * NKT32 * 64) / 256, 256, 0, stream>>>(w, whF, wlF);

    dim3 ggrid(TT / TM, kslices);   // (128, 8) = 1024 blocks
    gemm_kernel<<<ggrid, 256, 0, stream>>>(x, whF, wlF, partial, K_slice);

    routing_kernel<<<TT / 4, 256, 0, stream>>>(partial, bias, out_w, out_i, kslices);
}